// Round 13
// baseline (388.272 us; speedup 1.0000x reference)
//
#include <hip/hip_runtime.h>

#define N_ROWS 8192
#define D_DIM  1024
#define SM_SHIFT 4.0f

typedef _Float16 f16;
typedef _Float16 f16x8 __attribute__((ext_vector_type(8)));
typedef _Float16 f16x4 __attribute__((ext_vector_type(4)));
typedef float    f32x4 __attribute__((ext_vector_type(4)));

// offset=0 form only — the exact intrinsic usage verified in rounds 1-3,5-12.
__device__ __forceinline__ void gload16(const void* g, void* l) {
  __builtin_amdgcn_global_load_lds(
      (const __attribute__((address_space(1))) void*)g,
      (__attribute__((address_space(3))) void*)l, 16, 0, 0);
}

// XCD-chunked swizzle (m157): consecutive virtual ids land on one XCD.
__device__ __forceinline__ int xcd_swz(int bid, int nb) {
  return (bid & 7) * (nb >> 3) + (bid >> 3);
}

// 4x4 supertile of 256^2 tiles per co-XCD chunk: 4 A-panels + 4 B-panels
// (256x1024x2B = 512KB each) = 4MB = one XCD L2. Requires ny_t % 4 == 0.
__device__ __forceinline__ void tile2d4(int bid, int ny_t, int& nx, int& ny) {
  const int v = xcd_swz(bid, 32 * ny_t);
  const int g = v >> 4, w = v & 15;
  const int gpc = ny_t >> 2;
  const int gx = g / gpc, gy = g - gx * gpc;
  nx = gx * 4 + (w & 3);
  ny = gy * 4 + (w >> 2);
}

// ---------------------------------------------------------------- converts
__global__ __launch_bounds__(256) void f32_to_f16_kernel(
    const float* __restrict__ in, f16* __restrict__ out, int n4) {
  for (int i = blockIdx.x * blockDim.x + threadIdx.x; i < n4;
       i += gridDim.x * blockDim.x) {
    float4 x = ((const float4*)in)[i];
    f16x4 h = {(f16)x.x, (f16)x.y, (f16)x.z, (f16)x.w};
    ((f16x4*)out)[i] = h;
  }
}

__global__ __launch_bounds__(256) void transpose_w_kernel(
    const float* __restrict__ w0, const float* __restrict__ w1,
    const float* __restrict__ w2, f16* __restrict__ WT) {
  const float* W = (blockIdx.z == 0) ? w0 : (blockIdx.z == 1) ? w1 : w2;
  f16* T = WT + (size_t)blockIdx.z * D_DIM * D_DIM;
  __shared__ float tile[64][65];
  const int r0 = blockIdx.y * 64, c0 = blockIdx.x * 64;
  const int t = threadIdx.x;
#pragma unroll
  for (int rep = 0; rep < 16; ++rep) {
    int idx = rep * 256 + t;
    int r = idx >> 6, c = idx & 63;
    tile[r][c] = W[(size_t)(r0 + r) * D_DIM + (c0 + c)];
  }
  __syncthreads();
#pragma unroll
  for (int rep = 0; rep < 16; ++rep) {
    int idx = rep * 256 + t;
    int r = idx >> 6, c = idx & 63;
    T[(size_t)(c0 + r) * D_DIM + (r0 + c)] = (f16)tile[c][r];
  }
}

// --------------- 256^2 BK=64 faithful m201 4-phase/tile choreography
// Per phase: {ds_read subtile ; 2x gload smear ; [vmcnt] ; barrier1 ;
//             lgkm(0) ; setprio1 ; 16 MFMA (one quadrant) ; setprio0 ;
//             barrier2}. Reads issued BEFORE barrier1 -> LDS service
// overlaps barrier wait; the guard publishing each phase's data executed
// ONE PHASE EARLIER (off-by-one pipelining).
// Smear order (tile t stages t+1): P0:B01, P1:B23, P2:A02, P3:A13(+adv).
// Guards (chunk bookkeeping): t P0 vmcnt(2) drains t's A13 (outstanding =
// A13 + fresh B01) -> published by P0.barrier1 for P1's reads; t P3
// vmcnt(2) drains t+1's {B01,B23,A02} (outstanding = t+1's 8) -> published
// by P3.barrier1 for t+1 P0's reads (B all + A q0). Never vmcnt(0) except
// the tail. Write-after-read: all waves sit between the same barrier pair,
// and buf^1's readers all finished >=1 full tile earlier.
template <bool SWAP>
__device__ __forceinline__ void mainloop256(const f16* __restrict__ Ag, int lda,
                                            const f16* __restrict__ Bg,
                                            int ldbt, int nk, f16* LA, f16* LB,
                                            f32x4 (&acc)[8][4], int tid) {
  const int lane = tid & 63;
  const int wr = tid >> 8, wc = (tid >> 6) & 3;
  const int ro = lane & 15;
  const int jj0 = (((lane >> 4) ^ (ro & 7)) << 4);  // swizzled 16B col, kh=0
  const int rs = tid >> 3;                          // staging row (0..63)
  const int ce = ((tid & 7) ^ (rs & 7)) * 8;        // pre-swizzled src col
  const f16* a[4];
  const f16* b[4];
#pragma unroll
  for (int s = 0; s < 4; ++s) {
    a[s] = Ag + (size_t)(rs + 64 * s) * lda + ce;
    b[s] = Bg + (size_t)(rs + 64 * s) * ldbt + ce;
  }
  char* la = (char*)LA;
  char* lb = (char*)LB;
  const int t16 = tid * 16;

  auto stageB01 = [&](int buf) {
    char* B = lb + buf * 32768;
    gload16(b[0], B + t16);
    gload16(b[1], B + 8192 + t16);
  };
  auto stageB23 = [&](int buf) {
    char* B = lb + buf * 32768;
    gload16(b[2], B + 16384 + t16);
    gload16(b[3], B + 24576 + t16);
  };
  auto stageA02 = [&](int buf) {
    char* A = la + buf * 32768;
    gload16(a[0], A + t16);
    gload16(a[2], A + 16384 + t16);
  };
  auto stageA13 = [&](int buf) {  // last smear of the tile: advance pointers
    char* A = la + buf * 32768;
    gload16(a[1], A + 8192 + t16);
    gload16(a[3], A + 24576 + t16);
#pragma unroll
    for (int s = 0; s < 4; ++s) {
      a[s] += 64;
      b[s] += 64;
    }
  };

  f16x8 af[4], bf[4];
  auto readA = [&](const char* ab, int h, int jo) {
#pragma unroll
    for (int j = 0; j < 4; ++j)
      af[j] = *(const f16x8*)(ab + (wr * 128 + h * 64 + j * 16 + ro) * 128 + jo);
  };
  auto readB = [&](const char* bb, int jo) {
#pragma unroll
    for (int ni = 0; ni < 4; ++ni)
      bf[ni] = *(const f16x8*)(bb + (wc * 64 + ni * 16 + ro) * 128 + jo);
  };

#define PHASE_TAIL(H)                                                     \
  __builtin_amdgcn_s_barrier(); /* barrier1: publish guarded chunks */    \
  __builtin_amdgcn_sched_barrier(0);                                      \
  asm volatile("s_waitcnt lgkmcnt(0)" ::: "memory");                      \
  __builtin_amdgcn_sched_barrier(0);                                      \
  __builtin_amdgcn_s_setprio(1);                                          \
  _Pragma("unroll") for (int j = 0; j < 4; ++j)                           \
  _Pragma("unroll") for (int ni = 0; ni < 4; ++ni)                        \
      acc[(H) * 4 + j][ni] =                                              \
          SWAP ? __builtin_amdgcn_mfma_f32_16x16x32_f16(bf[ni], af[j],    \
                                                        acc[(H) * 4 + j][ni], \
                                                        0, 0, 0)          \
               : __builtin_amdgcn_mfma_f32_16x16x32_f16(af[j], bf[ni],    \
                                                        acc[(H) * 4 + j][ni], \
                                                        0, 0, 0);         \
  __builtin_amdgcn_s_setprio(0);                                          \
  __builtin_amdgcn_s_barrier(); /* barrier2: keep phase roles crisp */    \
  __builtin_amdgcn_sched_barrier(0);

  // prologue: stage tile 0 in smear order (pointers advance to tile 1);
  // vmcnt(2) leaves tile0's A13 outstanding (drained at t0 P0).
  stageB01(0);
  stageB23(0);
  stageA02(0);
  stageA13(0);
  asm volatile("s_waitcnt vmcnt(2)" ::: "memory");
  __builtin_amdgcn_s_barrier();
  __builtin_amdgcn_sched_barrier(0);

  for (int kt = 0; kt < nk; ++kt) {
    const int buf = kt & 1;
    const char* ab = la + buf * 32768;
    const char* bb = lb + buf * 32768;
    const bool more = (kt + 1 < nk);
    // ---- P0: reads B(kh0)+A(q0,kh0) [published @ t-1 P3]; smear B01;
    //      vmcnt(2) drains t's A13 (publish via barrier1 for P1).
    readB(bb, jj0);
    readA(ab, 0, jj0);
    if (more) {
      stageB01(buf ^ 1);
      asm volatile("s_waitcnt vmcnt(2)" ::: "memory");
    } else {
      asm volatile("s_waitcnt vmcnt(0)" ::: "memory");
    }
    PHASE_TAIL(0)
    // ---- P1: reads A(q1,kh0) [A13 published @ P0]; smear B23
    readA(ab, 1, jj0);
    if (more) stageB23(buf ^ 1);
    PHASE_TAIL(1)
    // ---- P2: reads B(kh1)+A(q0,kh1) [same chunks, long published]; A02
    readB(bb, jj0 ^ 64);
    readA(ab, 0, jj0 ^ 64);
    if (more) stageA02(buf ^ 1);
    PHASE_TAIL(0)
    // ---- P3: reads A(q1,kh1); smear A13; vmcnt(2) drains t+1's first 6
    //      (publish via barrier1 for t+1 P0's reads).
    readA(ab, 1, jj0 ^ 64);
    if (more) {
      stageA13(buf ^ 1);
      asm volatile("s_waitcnt vmcnt(2)" ::: "memory");
    }
    PHASE_TAIL(1)
  }
#undef PHASE_TAIL
}

#define ACC_INIT8(acc)                                \
  _Pragma("unroll") for (int i = 0; i < 8; ++i)       \
      _Pragma("unroll") for (int j = 0; j < 4; ++j)   \
          acc[i][j] = (f32x4){0.f, 0.f, 0.f, 0.f};

// ---------------------------------------------------------------- QKV GEMM
__global__ __launch_bounds__(512, 2) void gemm_qkv(
    const f16* __restrict__ Xh, const f16* __restrict__ WT,
    f16* __restrict__ Q, f16* __restrict__ Kh, f16* __restrict__ VT) {
  __shared__ f16 LA[2][16384], LB[2][16384];
  const int v = xcd_swz(blockIdx.x, 384);
  const int z = v >> 7, r = v & 127;
  const int nx = r & 3, ny = r >> 2;
  const int tid = threadIdx.x, lane = tid & 63;
  const int wr = tid >> 8, wc = (tid >> 6) & 3;
  const int ro = lane & 15, rq = (lane >> 4) * 4;

  const f16* A = Xh + (size_t)ny * 256 * D_DIM;
  const f16* B = WT + (size_t)z * D_DIM * D_DIM + (size_t)nx * 256 * D_DIM;

  f32x4 acc[8][4];
  ACC_INIT8(acc);
  if (z < 2) {
    mainloop256<true>(A, D_DIM, B, D_DIM, D_DIM / 64, &LA[0][0], &LB[0][0],
                      acc, tid);
    f16* C = z ? Kh : Q;
#pragma unroll
    for (int mi = 0; mi < 8; ++mi) {
      const size_t xr = ny * 256 + wr * 128 + mi * 16 + ro;
#pragma unroll
      for (int ni = 0; ni < 4; ++ni) {
        f16x4 pk;
#pragma unroll
        for (int rr = 0; rr < 4; ++rr) pk[rr] = (f16)acc[mi][ni][rr];
        *(f16x4*)&C[xr * D_DIM + nx * 256 + wc * 64 + ni * 16 + rq] = pk;
      }
    }
  } else {
    mainloop256<false>(A, D_DIM, B, D_DIM, D_DIM / 64, &LA[0][0], &LB[0][0],
                       acc, tid);
    // unswapped: lane holds 4 consecutive M-rows -> vectorized VT store
#pragma unroll
    for (int mi = 0; mi < 8; ++mi)
#pragma unroll
      for (int ni = 0; ni < 4; ++ni) {
        f16x4 pk;
#pragma unroll
        for (int rr = 0; rr < 4; ++rr) pk[rr] = (f16)acc[mi][ni][rr];
        const size_t d = nx * 256 + wc * 64 + ni * 16 + ro;
        *(f16x4*)&VT[d * N_ROWS + ny * 256 + wr * 128 + mi * 16 + rq] = pk;
      }
  }
}

// ------------------------------------------------ S = exp(QK^T/32 - SHIFT)
// Per-block row sums -> Lpart[row][128] (deterministic, no atomics).
__global__ __launch_bounds__(512, 2) void gemm_s_exp(
    const f16* __restrict__ Q, const f16* __restrict__ Kh, f16* __restrict__ S,
    float* __restrict__ Lpart, int nyb) {
  __shared__ f16 LA[2][16384], LB[2][16384];
  int nx, ny;
  tile2d4(blockIdx.x, nyb, nx, ny);
  const int tid = threadIdx.x, lane = tid & 63;
  const int wr = tid >> 8, wc = (tid >> 6) & 3;
  const int ro = lane & 15, rq = (lane >> 4) * 4;

  f32x4 acc[8][4];
  ACC_INIT8(acc);
  mainloop256<true>(Q + (size_t)ny * 256 * D_DIM, D_DIM,
                    Kh + (size_t)nx * 256 * D_DIM, D_DIM, D_DIM / 64,
                    &LA[0][0], &LB[0][0], acc, tid);

  const float sc = 0.03125f;  // 1/sqrt(1024)
#pragma unroll
  for (int mi = 0; mi < 8; ++mi) {
    const size_t q = ny * 256 + wr * 128 + mi * 16 + ro;
    f16* srow = S + q * N_ROWS + nx * 256 + wc * 64 + rq;
    float rs = 0.f;
#pragma unroll
    for (int ni = 0; ni < 4; ++ni) {
      f16x4 pk;
#pragma unroll
      for (int rr = 0; rr < 4; ++rr) {
        const float p = __expf(acc[mi][ni][rr] * sc - SM_SHIFT);
        rs += p;
        pk[rr] = (f16)p;
      }
      *(f16x4*)&srow[ni * 16] = pk;
    }
    rs += __shfl_xor(rs, 16, 64);
    rs += __shfl_xor(rs, 32, 64);
    if (lane < 16) Lpart[q * 128 + nx * 4 + wc] = rs;
  }
}

// ---------------------------------------------------------------- reduce l
__global__ __launch_bounds__(256) void reduce_l(const float* __restrict__ Lpart,
                                                float* __restrict__ linv,
                                                int rows) {
  const int w = (blockIdx.x * 256 + threadIdx.x) >> 6;  // one wave per row
  const int lane = threadIdx.x & 63;
  if (w >= rows) return;
  const float* p = Lpart + (size_t)w * 128;
  float s = p[lane] + p[lane + 64];
#pragma unroll
  for (int o = 32; o > 0; o >>= 1) s += __shfl_xor(s, o, 64);
  if (lane == 0) linv[w] = 1.0f / s;
}

// ---------------------------------------------------------------- PV
__global__ __launch_bounds__(512, 2) void gemm_pv(const f16* __restrict__ S,
                                                  const f16* __restrict__ VT,
                                                  float* __restrict__ Ppart,
                                                  int nyb, int KS, int chunk) {
  __shared__ f16 LA[2][16384], LB[2][16384];
  const int nid = xcd_swz(blockIdx.x, (int)gridDim.x);
  const int nx = nid & 3, ny = (nid >> 2) % nyb, z = (nid >> 2) / nyb;
  const int tid = threadIdx.x, lane = tid & 63;
  const int wr = tid >> 8, wc = (tid >> 6) & 3;
  const int ro = lane & 15, rq = (lane >> 4) * 4;

  f32x4 acc[8][4];
  ACC_INIT8(acc);
  mainloop256<true>(S + (size_t)ny * 256 * N_ROWS + (size_t)z * KS, N_ROWS,
                    VT + (size_t)nx * 256 * N_ROWS + (size_t)z * KS, N_ROWS,
                    KS / 64, &LA[0][0], &LB[0][0], acc, tid);

  float* out = Ppart + (size_t)z * chunk * D_DIM;
#pragma unroll
  for (int mi = 0; mi < 8; ++mi) {
    const size_t q = ny * 256 + wr * 128 + mi * 16 + ro;
#pragma unroll
    for (int ni = 0; ni < 4; ++ni)
      *(f32x4*)&out[q * D_DIM + nx * 256 + wc * 64 + ni * 16 + rq] =
          acc[mi][ni];
  }
}

// ---------------------------------------------------------------- reduce O
__global__ __launch_bounds__(256) void reduce_o(
    const float* __restrict__ Ppart, const float* __restrict__ linv,
    float* __restrict__ O, int rows, int sk) {
  const int n4 = rows * 256;  // float4 count (rows * 1024 / 4)
  const int stride = gridDim.x * blockDim.x;
  for (int i = blockIdx.x * 256 + threadIdx.x; i < n4; i += stride) {
    f32x4 s = ((const f32x4*)Ppart)[i];
    for (int t = 1; t < sk; ++t) s += ((const f32x4*)Ppart)[(size_t)t * n4 + i];
    const float il = linv[i >> 8];  // row = i*4/1024
    ((f32x4*)O)[i] = s * il;
  }
}

// ---------------------------------------------------------------- launch
extern "C" void kernel_launch(void* const* d_in, const int* in_sizes, int n_in,
                              void* d_out, int out_size, void* d_ws,
                              size_t ws_size, hipStream_t stream) {
  (void)in_sizes;
  (void)n_in;
  (void)out_size;
  const float* X = (const float*)d_in[0];
  const float* WQ = (const float*)d_in[1];
  const float* WK = (const float*)d_in[2];
  const float* WV = (const float*)d_in[3];
  float* O = (float*)d_out;

  // ---- workspace sizing: partials overlay the (dead-after-QKV) Xh/WT region
  const size_t fixedA = (size_t)N_ROWS * D_DIM * 2 + 3ull * D_DIM * D_DIM * 2;
  int chunk = 1024, sk = 1;
  const int pref[][2] = {{8192, 2}, {4096, 2}, {2048, 2}, {8192, 1},
                         {4096, 1}, {2048, 1}, {1024, 1}};
  for (int i = 0; i < 7; ++i) {
    const int c = pref[i][0], s = pref[i][1];
    size_t R = (size_t)s * c * D_DIM * 4;
    if (R < fixedA) R = fixedA;
    const size_t need = R + 3ull * N_ROWS * D_DIM * 2 + (size_t)c * N_ROWS * 2 +
                        (size_t)c * 128 * 4 + (size_t)c * 4 + 4096;
    if (need <= ws_size) {
      chunk = c;
      sk = s;
      break;
    }
  }

  char* base = (char*)d_ws;
  f16* Xh = (f16*)base;
  f16* WT = (f16*)(base + (size_t)N_ROWS * D_DIM * 2);
  float* Ppart = (float*)base;  // overlays Xh/WT (dead after QKV GEMMs)
  size_t R = (size_t)sk * chunk * D_DIM * 4;
  if (R < fixedA) R = fixedA;
  char* p = base + ((R + 255) & ~(size_t)255);
  f16* Q = (f16*)p;
  p += (size_t)N_ROWS * D_DIM * 2;
  f16* Kh = (f16*)p;
  p += (size_t)N_ROWS * D_DIM * 2;
  f16* VT = (f16*)p;
  p += (size_t)N_ROWS * D_DIM * 2;
  f16* S = (f16*)p;
  p += (size_t)chunk * N_ROWS * 2;
  float* Lpart = (float*)p;
  p += (size_t)chunk * 128 * 4;
  float* linv = (float*)p;

  f32_to_f16_kernel<<<2048, 256, 0, stream>>>(X, Xh, N_ROWS * D_DIM / 4);
  transpose_w_kernel<<<dim3(16, 16, 3), 256, 0, stream>>>(WQ, WK, WV, WT);
  gemm_qkv<<<384, 512, 0, stream>>>(Xh, WT, Q, Kh, VT);

  const int KS = N_ROWS / sk;
  for (int mc = 0; mc < N_ROWS; mc += chunk) {
    const int nyb = chunk / 256;
    gemm_s_exp<<<32 * nyb, 512, 0, stream>>>(Q + (size_t)mc * D_DIM, Kh, S,
                                             Lpart, nyb);
    reduce_l<<<(chunk + 3) / 4, 256, 0, stream>>>(Lpart, linv, chunk);
    gemm_pv<<<4 * nyb * sk, 512, 0, stream>>>(S, VT, Ppart, nyb, KS, chunk);
    reduce_o<<<1024, 256, 0, stream>>>(Ppart, linv, O + (size_t)mc * D_DIM,
                                       chunk, sk);
  }
}

// Round 14
// 382.891 us; speedup vs baseline: 1.0141x; 1.0141x over previous
//
#include <hip/hip_runtime.h>

#define N_ROWS 8192
#define D_DIM  1024
#define SM_SHIFT 4.0f

typedef _Float16 f16;
typedef _Float16 f16x8 __attribute__((ext_vector_type(8)));
typedef _Float16 f16x4 __attribute__((ext_vector_type(4)));
typedef float    f32x4 __attribute__((ext_vector_type(4)));

// offset=0 form only — the exact intrinsic usage verified in rounds 1-3,5-13.
__device__ __forceinline__ void gload16(const void* g, void* l) {
  __builtin_amdgcn_global_load_lds(
      (const __attribute__((address_space(1))) void*)g,
      (__attribute__((address_space(3))) void*)l, 16, 0, 0);
}

// XCD-chunked swizzle (m157): consecutive virtual ids land on one XCD.
__device__ __forceinline__ int xcd_swz(int bid, int nb) {
  return (bid & 7) * (nb >> 3) + (bid >> 3);
}

// 4x4 supertile of 256^2 tiles per co-XCD chunk: 4 A-panels + 4 B-panels
// (256x1024x2B = 512KB each) = 4MB = one XCD L2. Requires ny_t % 4 == 0.
__device__ __forceinline__ void tile2d4(int bid, int ny_t, int& nx, int& ny) {
  const int v = xcd_swz(bid, 32 * ny_t);
  const int g = v >> 4, w = v & 15;
  const int gpc = ny_t >> 2;
  const int gx = g / gpc, gy = g - gx * gpc;
  nx = gx * 4 + (w & 3);
  ny = gy * 4 + (w >> 2);
}

// ---------------------------------------------------------------- converts
__global__ __launch_bounds__(256) void f32_to_f16_kernel(
    const float* __restrict__ in, f16* __restrict__ out, int n4) {
  for (int i = blockIdx.x * blockDim.x + threadIdx.x; i < n4;
       i += gridDim.x * blockDim.x) {
    float4 x = ((const float4*)in)[i];
    f16x4 h = {(f16)x.x, (f16)x.y, (f16)x.z, (f16)x.w};
    ((f16x4*)out)[i] = h;
  }
}

__global__ __launch_bounds__(256) void transpose_w_kernel(
    const float* __restrict__ w0, const float* __restrict__ w1,
    const float* __restrict__ w2, f16* __restrict__ WT) {
  const float* W = (blockIdx.z == 0) ? w0 : (blockIdx.z == 1) ? w1 : w2;
  f16* T = WT + (size_t)blockIdx.z * D_DIM * D_DIM;
  __shared__ float tile[64][65];
  const int r0 = blockIdx.y * 64, c0 = blockIdx.x * 64;
  const int t = threadIdx.x;
#pragma unroll
  for (int rep = 0; rep < 16; ++rep) {
    int idx = rep * 256 + t;
    int r = idx >> 6, c = idx & 63;
    tile[r][c] = W[(size_t)(r0 + r) * D_DIM + (c0 + c)];
  }
  __syncthreads();
#pragma unroll
  for (int rep = 0; rep < 16; ++rep) {
    int idx = rep * 256 + t;
    int r = idx >> 6, c = idx & 63;
    T[(size_t)(c0 + r) * D_DIM + (r0 + c)] = (f16)tile[c][r];
  }
}

// ------------- 256^2 BK=64 4-phase loop, SINGLE barrier per tile
// r12 skeleton (best passing) with BARRIER_A removed. Per tile t:
//   P0: ds_read B(kh0)+A(q0,kh0); stage ALL 8 chunks of t+1; MFMA q0
//   P1: ds_read A(q1,kh0); MFMA q1
//   P2: ds_read B(kh1)+A(q0,kh1); MFMA q0
//   P3: ds_read A(q1,kh1); MFMA q1
//   end: vmcnt(0) [drains t+1's 8 gloads — issued 4 phases ago, ~free]
//        s_barrier [publishes t+1 (RAW) + licenses restage (WAR: every
//        wave's reads of buf returned before its P3 lgkmcnt(0))]
// Every ds_read of tile t is preceded in program order by t-1's
// {vmcnt(0) -> barrier -> sched_barrier(0)} — r8 race class excluded.
// Waves drift freely across all 4 phases -> cross-wave LDS/MFMA overlap.
template <bool SWAP>
__device__ __forceinline__ void mainloop256(const f16* __restrict__ Ag, int lda,
                                            const f16* __restrict__ Bg,
                                            int ldbt, int nk, f16* LA, f16* LB,
                                            f32x4 (&acc)[8][4], int tid) {
  const int lane = tid & 63;
  const int wr = tid >> 8, wc = (tid >> 6) & 3;
  const int ro = lane & 15;
  const int jj0 = (((lane >> 4) ^ (ro & 7)) << 4);  // swizzled 16B col, kh=0
  const int rs = tid >> 3;                          // staging row (0..63)
  const int ce = ((tid & 7) ^ (rs & 7)) * 8;        // pre-swizzled src col
  const f16* a[4];
  const f16* b[4];
#pragma unroll
  for (int s = 0; s < 4; ++s) {
    a[s] = Ag + (size_t)(rs + 64 * s) * lda + ce;
    b[s] = Bg + (size_t)(rs + 64 * s) * ldbt + ce;
  }
  char* la = (char*)LA;
  char* lb = (char*)LB;
  const int t16 = tid * 16;

  auto stage_all = [&](int buf) {  // 8 loads: next K64-tile (A 32KB + B 32KB)
    char* A = la + buf * 32768;
    char* B = lb + buf * 32768;
#pragma unroll
    for (int s = 0; s < 4; ++s) {
      gload16(a[s], A + s * 8192 + t16);
      gload16(b[s], B + s * 8192 + t16);
    }
#pragma unroll
    for (int s = 0; s < 4; ++s) {
      a[s] += 64;
      b[s] += 64;
    }
  };

  f16x8 af[4], bf[4];
  auto readA = [&](const char* ab, int h, int jo) {
#pragma unroll
    for (int j = 0; j < 4; ++j)
      af[j] = *(const f16x8*)(ab + (wr * 128 + h * 64 + j * 16 + ro) * 128 + jo);
  };
  auto readB = [&](const char* bb, int jo) {
#pragma unroll
    for (int ni = 0; ni < 4; ++ni)
      bf[ni] = *(const f16x8*)(bb + (wc * 64 + ni * 16 + ro) * 128 + jo);
  };

#define MFMA_CLUSTER(H)                                                   \
  asm volatile("s_waitcnt lgkmcnt(0)" ::: "memory");                      \
  __builtin_amdgcn_sched_barrier(0);                                      \
  __builtin_amdgcn_s_setprio(1);                                          \
  _Pragma("unroll") for (int j = 0; j < 4; ++j)                           \
  _Pragma("unroll") for (int ni = 0; ni < 4; ++ni)                        \
      acc[(H) * 4 + j][ni] =                                              \
          SWAP ? __builtin_amdgcn_mfma_f32_16x16x32_f16(bf[ni], af[j],    \
                                                        acc[(H) * 4 + j][ni], \
                                                        0, 0, 0)          \
               : __builtin_amdgcn_mfma_f32_16x16x32_f16(af[j], bf[ni],    \
                                                        acc[(H) * 4 + j][ni], \
                                                        0, 0, 0);         \
  __builtin_amdgcn_s_setprio(0);

  // prologue: tile 0 staged + drained (pointers advance to tile 1)
  stage_all(0);
  asm volatile("s_waitcnt vmcnt(0)" ::: "memory");
  __builtin_amdgcn_s_barrier();
  __builtin_amdgcn_sched_barrier(0);

  for (int kt = 0; kt < nk; ++kt) {
    const int buf = kt & 1;
    const char* ab = la + buf * 32768;
    const char* bb = lb + buf * 32768;
    // ---- P0: reads q0/kh0 (published by prev barrier), stage all of t+1
    readB(bb, jj0);
    readA(ab, 0, jj0);
    if (kt + 1 < nk) stage_all(buf ^ 1);
    MFMA_CLUSTER(0)
    // ---- P1
    readA(ab, 1, jj0);
    MFMA_CLUSTER(1)
    // ---- P2
    readB(bb, jj0 ^ 64);
    readA(ab, 0, jj0 ^ 64);
    MFMA_CLUSTER(0)
    // ---- P3
    readA(ab, 1, jj0 ^ 64);
    MFMA_CLUSTER(1)
    // ---- tile end: drain t+1's 4-phase-old loads, publish, license
    asm volatile("s_waitcnt vmcnt(0)" ::: "memory");
    __builtin_amdgcn_s_barrier();
    __builtin_amdgcn_sched_barrier(0);
  }
#undef MFMA_CLUSTER
}

#define ACC_INIT8(acc)                                \
  _Pragma("unroll") for (int i = 0; i < 8; ++i)       \
      _Pragma("unroll") for (int j = 0; j < 4; ++j)   \
          acc[i][j] = (f32x4){0.f, 0.f, 0.f, 0.f};

// ---------------------------------------------------------------- QKV GEMM
__global__ __launch_bounds__(512, 2) void gemm_qkv(
    const f16* __restrict__ Xh, const f16* __restrict__ WT,
    f16* __restrict__ Q, f16* __restrict__ Kh, f16* __restrict__ VT) {
  __shared__ f16 LA[2][16384], LB[2][16384];
  const int v = xcd_swz(blockIdx.x, 384);
  const int z = v >> 7, r = v & 127;
  const int nx = r & 3, ny = r >> 2;
  const int tid = threadIdx.x, lane = tid & 63;
  const int wr = tid >> 8, wc = (tid >> 6) & 3;
  const int ro = lane & 15, rq = (lane >> 4) * 4;

  const f16* A = Xh + (size_t)ny * 256 * D_DIM;
  const f16* B = WT + (size_t)z * D_DIM * D_DIM + (size_t)nx * 256 * D_DIM;

  f32x4 acc[8][4];
  ACC_INIT8(acc);
  if (z < 2) {
    mainloop256<true>(A, D_DIM, B, D_DIM, D_DIM / 64, &LA[0][0], &LB[0][0],
                      acc, tid);
    f16* C = z ? Kh : Q;
#pragma unroll
    for (int mi = 0; mi < 8; ++mi) {
      const size_t xr = ny * 256 + wr * 128 + mi * 16 + ro;
#pragma unroll
      for (int ni = 0; ni < 4; ++ni) {
        f16x4 pk;
#pragma unroll
        for (int rr = 0; rr < 4; ++rr) pk[rr] = (f16)acc[mi][ni][rr];
        *(f16x4*)&C[xr * D_DIM + nx * 256 + wc * 64 + ni * 16 + rq] = pk;
      }
    }
  } else {
    mainloop256<false>(A, D_DIM, B, D_DIM, D_DIM / 64, &LA[0][0], &LB[0][0],
                       acc, tid);
    // unswapped: lane holds 4 consecutive M-rows -> vectorized VT store
#pragma unroll
    for (int mi = 0; mi < 8; ++mi)
#pragma unroll
      for (int ni = 0; ni < 4; ++ni) {
        f16x4 pk;
#pragma unroll
        for (int rr = 0; rr < 4; ++rr) pk[rr] = (f16)acc[mi][ni][rr];
        const size_t d = nx * 256 + wc * 64 + ni * 16 + ro;
        *(f16x4*)&VT[d * N_ROWS + ny * 256 + wr * 128 + mi * 16 + rq] = pk;
      }
  }
}

// ------------------------------------------------ S = exp(QK^T/32 - SHIFT)
// Per-block row sums -> Lpart[row][128] (deterministic, no atomics).
__global__ __launch_bounds__(512, 2) void gemm_s_exp(
    const f16* __restrict__ Q, const f16* __restrict__ Kh, f16* __restrict__ S,
    float* __restrict__ Lpart, int nyb) {
  __shared__ f16 LA[2][16384], LB[2][16384];
  int nx, ny;
  tile2d4(blockIdx.x, nyb, nx, ny);
  const int tid = threadIdx.x, lane = tid & 63;
  const int wr = tid >> 8, wc = (tid >> 6) & 3;
  const int ro = lane & 15, rq = (lane >> 4) * 4;

  f32x4 acc[8][4];
  ACC_INIT8(acc);
  mainloop256<true>(Q + (size_t)ny * 256 * D_DIM, D_DIM,
                    Kh + (size_t)nx * 256 * D_DIM, D_DIM, D_DIM / 64,
                    &LA[0][0], &LB[0][0], acc, tid);

  const float sc = 0.03125f;  // 1/sqrt(1024)
#pragma unroll
  for (int mi = 0; mi < 8; ++mi) {
    const size_t q = ny * 256 + wr * 128 + mi * 16 + ro;
    f16* srow = S + q * N_ROWS + nx * 256 + wc * 64 + rq;
    float rs = 0.f;
#pragma unroll
    for (int ni = 0; ni < 4; ++ni) {
      f16x4 pk;
#pragma unroll
      for (int rr = 0; rr < 4; ++rr) {
        const float p = __expf(acc[mi][ni][rr] * sc - SM_SHIFT);
        rs += p;
        pk[rr] = (f16)p;
      }
      *(f16x4*)&srow[ni * 16] = pk;
    }
    rs += __shfl_xor(rs, 16, 64);
    rs += __shfl_xor(rs, 32, 64);
    if (lane < 16) Lpart[q * 128 + nx * 4 + wc] = rs;
  }
}

// ---------------------------------------------------------------- reduce l
__global__ __launch_bounds__(256) void reduce_l(const float* __restrict__ Lpart,
                                                float* __restrict__ linv,
                                                int rows) {
  const int w = (blockIdx.x * 256 + threadIdx.x) >> 6;  // one wave per row
  const int lane = threadIdx.x & 63;
  if (w >= rows) return;
  const float* p = Lpart + (size_t)w * 128;
  float s = p[lane] + p[lane + 64];
#pragma unroll
  for (int o = 32; o > 0; o >>= 1) s += __shfl_xor(s, o, 64);
  if (lane == 0) linv[w] = 1.0f / s;
}

// ---------------------------------------------------------------- PV
__global__ __launch_bounds__(512, 2) void gemm_pv(const f16* __restrict__ S,
                                                  const f16* __restrict__ VT,
                                                  float* __restrict__ Ppart,
                                                  int nyb, int KS, int chunk) {
  __shared__ f16 LA[2][16384], LB[2][16384];
  const int nid = xcd_swz(blockIdx.x, (int)gridDim.x);
  const int nx = nid & 3, ny = (nid >> 2) % nyb, z = (nid >> 2) / nyb;
  const int tid = threadIdx.x, lane = tid & 63;
  const int wr = tid >> 8, wc = (tid >> 6) & 3;
  const int ro = lane & 15, rq = (lane >> 4) * 4;

  f32x4 acc[8][4];
  ACC_INIT8(acc);
  mainloop256<true>(S + (size_t)ny * 256 * N_ROWS + (size_t)z * KS, N_ROWS,
                    VT + (size_t)nx * 256 * N_ROWS + (size_t)z * KS, N_ROWS,
                    KS / 64, &LA[0][0], &LB[0][0], acc, tid);

  float* out = Ppart + (size_t)z * chunk * D_DIM;
#pragma unroll
  for (int mi = 0; mi < 8; ++mi) {
    const size_t q = ny * 256 + wr * 128 + mi * 16 + ro;
#pragma unroll
    for (int ni = 0; ni < 4; ++ni)
      *(f32x4*)&out[q * D_DIM + nx * 256 + wc * 64 + ni * 16 + rq] =
          acc[mi][ni];
  }
}

// ---------------------------------------------------------------- reduce O
__global__ __launch_bounds__(256) void reduce_o(
    const float* __restrict__ Ppart, const float* __restrict__ linv,
    float* __restrict__ O, int rows, int sk) {
  const int n4 = rows * 256;  // float4 count (rows * 1024 / 4)
  const int stride = gridDim.x * blockDim.x;
  for (int i = blockIdx.x * 256 + threadIdx.x; i < n4; i += stride) {
    f32x4 s = ((const f32x4*)Ppart)[i];
    for (int t = 1; t < sk; ++t) s += ((const f32x4*)Ppart)[(size_t)t * n4 + i];
    const float il = linv[i >> 8];  // row = i*4/1024
    ((f32x4*)O)[i] = s * il;
  }
}

// ---------------------------------------------------------------- launch
extern "C" void kernel_launch(void* const* d_in, const int* in_sizes, int n_in,
                              void* d_out, int out_size, void* d_ws,
                              size_t ws_size, hipStream_t stream) {
  (void)in_sizes;
  (void)n_in;
  (void)out_size;
  const float* X = (const float*)d_in[0];
  const float* WQ = (const float*)d_in[1];
  const float* WK = (const float*)d_in[2];
  const float* WV = (const float*)d_in[3];
  float* O = (float*)d_out;

  // ---- workspace sizing: partials overlay the (dead-after-QKV) Xh/WT region
  const size_t fixedA = (size_t)N_ROWS * D_DIM * 2 + 3ull * D_DIM * D_DIM * 2;
  int chunk = 1024, sk = 1;
  const int pref[][2] = {{8192, 2}, {4096, 2}, {2048, 2}, {8192, 1},
                         {4096, 1}, {2048, 1}, {1024, 1}};
  for (int i = 0; i < 7; ++i) {
    const int c = pref[i][0], s = pref[i][1];
    size_t R = (size_t)s * c * D_DIM * 4;
    if (R < fixedA) R = fixedA;
    const size_t need = R + 3ull * N_ROWS * D_DIM * 2 + (size_t)c * N_ROWS * 2 +
                        (size_t)c * 128 * 4 + (size_t)c * 4 + 4096;
    if (need <= ws_size) {
      chunk = c;
      sk = s;
      break;
    }
  }

  char* base = (char*)d_ws;
  f16* Xh = (f16*)base;
  f16* WT = (f16*)(base + (size_t)N_ROWS * D_DIM * 2);
  float* Ppart = (float*)base;  // overlays Xh/WT (dead after QKV GEMMs)
  size_t R = (size_t)sk * chunk * D_DIM * 4;
  if (R < fixedA) R = fixedA;
  char* p = base + ((R + 255) & ~(size_t)255);
  f16* Q = (f16*)p;
  p += (size_t)N_ROWS * D_DIM * 2;
  f16* Kh = (f16*)p;
  p += (size_t)N_ROWS * D_DIM * 2;
  f16* VT = (f16*)p;
  p += (size_t)N_ROWS * D_DIM * 2;
  f16* S = (f16*)p;
  p += (size_t)chunk * N_ROWS * 2;
  float* Lpart = (float*)p;
  p += (size_t)chunk * 128 * 4;
  float* linv = (float*)p;

  f32_to_f16_kernel<<<2048, 256, 0, stream>>>(X, Xh, N_ROWS * D_DIM / 4);
  transpose_w_kernel<<<dim3(16, 16, 3), 256, 0, stream>>>(WQ, WK, WV, WT);
  gemm_qkv<<<384, 512, 0, stream>>>(Xh, WT, Q, Kh, VT);

  const int KS = N_ROWS / sk;
  for (int mc = 0; mc < N_ROWS; mc += chunk) {
    const int nyb = chunk / 256;
    gemm_s_exp<<<32 * nyb, 512, 0, stream>>>(Q + (size_t)mc * D_DIM, Kh, S,
                                             Lpart, nyb);
    reduce_l<<<(chunk + 3) / 4, 256, 0, stream>>>(Lpart, linv, chunk);
    gemm_pv<<<4 * nyb * sk, 512, 0, stream>>>(S, VT, Ppart, nyb, KS, chunk);
    reduce_o<<<1024, 256, 0, stream>>>(Ppart, linv, O + (size_t)mc * D_DIM,
                                       chunk, sk);
  }
}

// Round 15
// 369.254 us; speedup vs baseline: 1.0515x; 1.0369x over previous
//
#include <hip/hip_runtime.h>

#define N_ROWS 8192
#define D_DIM  1024
#define SM_SHIFT 4.0f

typedef _Float16 f16;
typedef _Float16 f16x8 __attribute__((ext_vector_type(8)));
typedef _Float16 f16x4 __attribute__((ext_vector_type(4)));
typedef float    f32x4 __attribute__((ext_vector_type(4)));

// offset=0 form only — the exact intrinsic usage verified in rounds 1-3,5-14.
__device__ __forceinline__ void gload16(const void* g, void* l) {
  __builtin_amdgcn_global_load_lds(
      (const __attribute__((address_space(1))) void*)g,
      (__attribute__((address_space(3))) void*)l, 16, 0, 0);
}

// XCD-chunked swizzle (m157): consecutive virtual ids land on one XCD.
__device__ __forceinline__ int xcd_swz(int bid, int nb) {
  return (bid & 7) * (nb >> 3) + (bid >> 3);
}

// 4x4 supertile of 256^2 tiles per co-XCD chunk: 4 A-panels + 4 B-panels
// (256x1024x2B = 512KB each) = 4MB = one XCD L2. Requires ny_t % 4 == 0.
__device__ __forceinline__ void tile2d4(int bid, int ny_t, int& nx, int& ny) {
  const int v = xcd_swz(bid, 32 * ny_t);
  const int g = v >> 4, w = v & 15;
  const int gpc = ny_t >> 2;
  const int gx = g / gpc, gy = g - gx * gpc;
  nx = gx * 4 + (w & 3);
  ny = gy * 4 + (w >> 2);
}

// ---------------------------------------------------------------- converts
__global__ __launch_bounds__(256) void f32_to_f16_kernel(
    const float* __restrict__ in, f16* __restrict__ out, int n4) {
  for (int i = blockIdx.x * blockDim.x + threadIdx.x; i < n4;
       i += gridDim.x * blockDim.x) {
    float4 x = ((const float4*)in)[i];
    f16x4 h = {(f16)x.x, (f16)x.y, (f16)x.z, (f16)x.w};
    ((f16x4*)out)[i] = h;
  }
}

__global__ __launch_bounds__(256) void transpose_w_kernel(
    const float* __restrict__ w0, const float* __restrict__ w1,
    const float* __restrict__ w2, f16* __restrict__ WT) {
  const float* W = (blockIdx.z == 0) ? w0 : (blockIdx.z == 1) ? w1 : w2;
  f16* T = WT + (size_t)blockIdx.z * D_DIM * D_DIM;
  __shared__ float tile[64][65];
  const int r0 = blockIdx.y * 64, c0 = blockIdx.x * 64;
  const int t = threadIdx.x;
#pragma unroll
  for (int rep = 0; rep < 16; ++rep) {
    int idx = rep * 256 + t;
    int r = idx >> 6, c = idx & 63;
    tile[r][c] = W[(size_t)(r0 + r) * D_DIM + (c0 + c)];
  }
  __syncthreads();
#pragma unroll
  for (int rep = 0; rep < 16; ++rep) {
    int idx = rep * 256 + t;
    int r = idx >> 6, c = idx & 63;
    T[(size_t)(c0 + r) * D_DIM + (r0 + c)] = (f16)tile[c][r];
  }
}

// ------------- 256^2 BK=64 4-phase loop, r12 guards, UNPINNED schedule
// Identical program order + guards to r12 (best passing: 2 barriers/tile,
// vmcnt(4)@P0 publishes t's A1,A3; vmcnt(2)@P3 publishes t+1's first 6).
// REMOVED vs r12: all sched_barrier(0) pins and the per-cluster full
// lgkmcnt(0) drains (m141: order-pinning costs ~40%; m97: compiler emits
// fine-grained counted lgkmcnt for ds_read->MFMA on its own).
// Correctness without pins: every guard is asm with "memory" clobber ->
// ds_read/gload cannot cross it (RAW/publishing preserved, r8 race class
// excluded by program order); every P3 ds_read is consumed by an MFMA
// before BARRIER_B, so all reads returned before restage license (WAR).
template <bool SWAP>
__device__ __forceinline__ void mainloop256(const f16* __restrict__ Ag, int lda,
                                            const f16* __restrict__ Bg,
                                            int ldbt, int nk, f16* LA, f16* LB,
                                            f32x4 (&acc)[8][4], int tid) {
  const int lane = tid & 63;
  const int wr = tid >> 8, wc = (tid >> 6) & 3;
  const int ro = lane & 15;
  const int jj0 = (((lane >> 4) ^ (ro & 7)) << 4);  // swizzled 16B col, kh=0
  const int rs = tid >> 3;                          // staging row (0..63)
  const int ce = ((tid & 7) ^ (rs & 7)) * 8;        // pre-swizzled src col
  const f16* a[4];
  const f16* b[4];
#pragma unroll
  for (int s = 0; s < 4; ++s) {
    a[s] = Ag + (size_t)(rs + 64 * s) * lda + ce;
    b[s] = Bg + (size_t)(rs + 64 * s) * ldbt + ce;
  }
  char* la = (char*)LA;
  char* lb = (char*)LB;
  const int t16 = tid * 16;

  // issue order within a tile: [A0,A2,B0,B1] (P0) then [B2,B3,A1,A3] (P1)
  auto stage_p0 = [&](int buf) {
    char* A = la + buf * 32768;
    char* B = lb + buf * 32768;
    gload16(a[0], A + t16);
    gload16(a[2], A + 16384 + t16);
    gload16(b[0], B + t16);
    gload16(b[1], B + 8192 + t16);
  };
  auto stage_p1 = [&](int buf) {
    char* A = la + buf * 32768;
    char* B = lb + buf * 32768;
    gload16(b[2], B + 16384 + t16);
    gload16(b[3], B + 24576 + t16);
    gload16(a[1], A + 8192 + t16);
    gload16(a[3], A + 24576 + t16);
#pragma unroll
    for (int s = 0; s < 4; ++s) {
      a[s] += 64;
      b[s] += 64;
    }
  };

  f16x8 af[4], bf[4];
  auto readA = [&](const char* ab, int h, int jo) {
#pragma unroll
    for (int j = 0; j < 4; ++j)
      af[j] = *(const f16x8*)(ab + (wr * 128 + h * 64 + j * 16 + ro) * 128 + jo);
  };
  auto readB = [&](const char* bb, int jo) {
#pragma unroll
    for (int ni = 0; ni < 4; ++ni)
      bf[ni] = *(const f16x8*)(bb + (wc * 64 + ni * 16 + ro) * 128 + jo);
  };

#define MFMA_CLUSTER(H)                                                   \
  __builtin_amdgcn_s_setprio(1);                                          \
  _Pragma("unroll") for (int j = 0; j < 4; ++j)                           \
  _Pragma("unroll") for (int ni = 0; ni < 4; ++ni)                        \
      acc[(H) * 4 + j][ni] =                                              \
          SWAP ? __builtin_amdgcn_mfma_f32_16x16x32_f16(bf[ni], af[j],    \
                                                        acc[(H) * 4 + j][ni], \
                                                        0, 0, 0)          \
               : __builtin_amdgcn_mfma_f32_16x16x32_f16(af[j], bf[ni],    \
                                                        acc[(H) * 4 + j][ni], \
                                                        0, 0, 0);         \
  __builtin_amdgcn_s_setprio(0);

  // prologue: tile 0 fully staged + drained (pointers advance to tile 1)
  stage_p0(0);
  stage_p1(0);
  asm volatile("s_waitcnt vmcnt(0)" ::: "memory");
  __builtin_amdgcn_s_barrier();

  for (int kt = 0; kt < nk; ++kt) {
    const int buf = kt & 1;
    const char* ab = la + buf * 32768;
    const char* bb = lb + buf * 32768;
    const bool more = (kt + 1 < nk);
    // ---- P0: reads q0/kh0 (published by prev BARRIER_B / prologue);
    //      stage first 4 of t+1; vmcnt(4) drains t's A1,A3; BARRIER_A.
    readB(bb, jj0);
    readA(ab, 0, jj0);
    if (more) {
      stage_p0(buf ^ 1);
      asm volatile("s_waitcnt vmcnt(4)" ::: "memory");
    } else {
      asm volatile("s_waitcnt vmcnt(0)" ::: "memory");
    }
    __builtin_amdgcn_s_barrier();  // BARRIER_A: A1,A3 visible to all waves
    MFMA_CLUSTER(0)
    // ---- P1: reads q1/kh0 (A1,A3 licensed by BARRIER_A); stage last 4
    readA(ab, 1, jj0);
    if (more) stage_p1(buf ^ 1);
    MFMA_CLUSTER(1)
    // ---- P2: reads q0/kh1 (same chunks, long published)
    readB(bb, jj0 ^ 64);
    readA(ab, 0, jj0 ^ 64);
    MFMA_CLUSTER(0)
    // ---- P3: reads q1/kh1
    readA(ab, 1, jj0 ^ 64);
    MFMA_CLUSTER(1)
    // vmcnt(2): t+1's first 6 chunks landed (no-op at tail); BARRIER_B
    // publishes them AND licenses t+1's gloads (all reads consumed above).
    asm volatile("s_waitcnt vmcnt(2)" ::: "memory");
    __builtin_amdgcn_s_barrier();  // BARRIER_B
  }
#undef MFMA_CLUSTER
}

#define ACC_INIT8(acc)                                \
  _Pragma("unroll") for (int i = 0; i < 8; ++i)       \
      _Pragma("unroll") for (int j = 0; j < 4; ++j)   \
          acc[i][j] = (f32x4){0.f, 0.f, 0.f, 0.f};

// ---------------------------------------------------------------- QKV GEMM
__global__ __launch_bounds__(512, 2) void gemm_qkv(
    const f16* __restrict__ Xh, const f16* __restrict__ WT,
    f16* __restrict__ Q, f16* __restrict__ Kh, f16* __restrict__ VT) {
  __shared__ f16 LA[2][16384], LB[2][16384];
  const int v = xcd_swz(blockIdx.x, 384);
  const int z = v >> 7, r = v & 127;
  const int nx = r & 3, ny = r >> 2;
  const int tid = threadIdx.x, lane = tid & 63;
  const int wr = tid >> 8, wc = (tid >> 6) & 3;
  const int ro = lane & 15, rq = (lane >> 4) * 4;

  const f16* A = Xh + (size_t)ny * 256 * D_DIM;
  const f16* B = WT + (size_t)z * D_DIM * D_DIM + (size_t)nx * 256 * D_DIM;

  f32x4 acc[8][4];
  ACC_INIT8(acc);
  if (z < 2) {
    mainloop256<true>(A, D_DIM, B, D_DIM, D_DIM / 64, &LA[0][0], &LB[0][0],
                      acc, tid);
    f16* C = z ? Kh : Q;
#pragma unroll
    for (int mi = 0; mi < 8; ++mi) {
      const size_t xr = ny * 256 + wr * 128 + mi * 16 + ro;
#pragma unroll
      for (int ni = 0; ni < 4; ++ni) {
        f16x4 pk;
#pragma unroll
        for (int rr = 0; rr < 4; ++rr) pk[rr] = (f16)acc[mi][ni][rr];
        *(f16x4*)&C[xr * D_DIM + nx * 256 + wc * 64 + ni * 16 + rq] = pk;
      }
    }
  } else {
    mainloop256<false>(A, D_DIM, B, D_DIM, D_DIM / 64, &LA[0][0], &LB[0][0],
                       acc, tid);
    // unswapped: lane holds 4 consecutive M-rows -> vectorized VT store
#pragma unroll
    for (int mi = 0; mi < 8; ++mi)
#pragma unroll
      for (int ni = 0; ni < 4; ++ni) {
        f16x4 pk;
#pragma unroll
        for (int rr = 0; rr < 4; ++rr) pk[rr] = (f16)acc[mi][ni][rr];
        const size_t d = nx * 256 + wc * 64 + ni * 16 + ro;
        *(f16x4*)&VT[d * N_ROWS + ny * 256 + wr * 128 + mi * 16 + rq] = pk;
      }
  }
}

// ------------------------------------------------ S = exp(QK^T/32 - SHIFT)
// Per-block row sums -> Lpart[row][128] (deterministic, no atomics).
__global__ __launch_bounds__(512, 2) void gemm_s_exp(
    const f16* __restrict__ Q, const f16* __restrict__ Kh, f16* __restrict__ S,
    float* __restrict__ Lpart, int nyb) {
  __shared__ f16 LA[2][16384], LB[2][16384];
  int nx, ny;
  tile2d4(blockIdx.x, nyb, nx, ny);
  const int tid = threadIdx.x, lane = tid & 63;
  const int wr = tid >> 8, wc = (tid >> 6) & 3;
  const int ro = lane & 15, rq = (lane >> 4) * 4;

  f32x4 acc[8][4];
  ACC_INIT8(acc);
  mainloop256<true>(Q + (size_t)ny * 256 * D_DIM, D_DIM,
                    Kh + (size_t)nx * 256 * D_DIM, D_DIM, D_DIM / 64,
                    &LA[0][0], &LB[0][0], acc, tid);

  const float sc = 0.03125f;  // 1/sqrt(1024)
#pragma unroll
  for (int mi = 0; mi < 8; ++mi) {
    const size_t q = ny * 256 + wr * 128 + mi * 16 + ro;
    f16* srow = S + q * N_ROWS + nx * 256 + wc * 64 + rq;
    float rs = 0.f;
#pragma unroll
    for (int ni = 0; ni < 4; ++ni) {
      f16x4 pk;
#pragma unroll
      for (int rr = 0; rr < 4; ++rr) {
        const float p = __expf(acc[mi][ni][rr] * sc - SM_SHIFT);
        rs += p;
        pk[rr] = (f16)p;
      }
      *(f16x4*)&srow[ni * 16] = pk;
    }
    rs += __shfl_xor(rs, 16, 64);
    rs += __shfl_xor(rs, 32, 64);
    if (lane < 16) Lpart[q * 128 + nx * 4 + wc] = rs;
  }
}

// ---------------------------------------------------------------- reduce l
__global__ __launch_bounds__(256) void reduce_l(const float* __restrict__ Lpart,
                                                float* __restrict__ linv,
                                                int rows) {
  const int w = (blockIdx.x * 256 + threadIdx.x) >> 6;  // one wave per row
  const int lane = threadIdx.x & 63;
  if (w >= rows) return;
  const float* p = Lpart + (size_t)w * 128;
  float s = p[lane] + p[lane + 64];
#pragma unroll
  for (int o = 32; o > 0; o >>= 1) s += __shfl_xor(s, o, 64);
  if (lane == 0) linv[w] = 1.0f / s;
}

// ---------------------------------------------------------------- PV
__global__ __launch_bounds__(512, 2) void gemm_pv(const f16* __restrict__ S,
                                                  const f16* __restrict__ VT,
                                                  float* __restrict__ Ppart,
                                                  int nyb, int KS, int chunk) {
  __shared__ f16 LA[2][16384], LB[2][16384];
  const int nid = xcd_swz(blockIdx.x, (int)gridDim.x);
  const int nx = nid & 3, ny = (nid >> 2) % nyb, z = (nid >> 2) / nyb;
  const int tid = threadIdx.x, lane = tid & 63;
  const int wr = tid >> 8, wc = (tid >> 6) & 3;
  const int ro = lane & 15, rq = (lane >> 4) * 4;

  f32x4 acc[8][4];
  ACC_INIT8(acc);
  mainloop256<true>(S + (size_t)ny * 256 * N_ROWS + (size_t)z * KS, N_ROWS,
                    VT + (size_t)nx * 256 * N_ROWS + (size_t)z * KS, N_ROWS,
                    KS / 64, &LA[0][0], &LB[0][0], acc, tid);

  float* out = Ppart + (size_t)z * chunk * D_DIM;
#pragma unroll
  for (int mi = 0; mi < 8; ++mi) {
    const size_t q = ny * 256 + wr * 128 + mi * 16 + ro;
#pragma unroll
    for (int ni = 0; ni < 4; ++ni)
      *(f32x4*)&out[q * D_DIM + nx * 256 + wc * 64 + ni * 16 + rq] =
          acc[mi][ni];
  }
}

// ---------------------------------------------------------------- reduce O
__global__ __launch_bounds__(256) void reduce_o(
    const float* __restrict__ Ppart, const float* __restrict__ linv,
    float* __restrict__ O, int rows, int sk) {
  const int n4 = rows * 256;  // float4 count (rows * 1024 / 4)
  const int stride = gridDim.x * blockDim.x;
  for (int i = blockIdx.x * 256 + threadIdx.x; i < n4; i += stride) {
    f32x4 s = ((const f32x4*)Ppart)[i];
    for (int t = 1; t < sk; ++t) s += ((const f32x4*)Ppart)[(size_t)t * n4 + i];
    const float il = linv[i >> 8];  // row = i*4/1024
    ((f32x4*)O)[i] = s * il;
  }
}

// ---------------------------------------------------------------- launch
extern "C" void kernel_launch(void* const* d_in, const int* in_sizes, int n_in,
                              void* d_out, int out_size, void* d_ws,
                              size_t ws_size, hipStream_t stream) {
  (void)in_sizes;
  (void)n_in;
  (void)out_size;
  const float* X = (const float*)d_in[0];
  const float* WQ = (const float*)d_in[1];
  const float* WK = (const float*)d_in[2];
  const float* WV = (const float*)d_in[3];
  float* O = (float*)d_out;

  // ---- workspace sizing: partials overlay the (dead-after-QKV) Xh/WT region
  const size_t fixedA = (size_t)N_ROWS * D_DIM * 2 + 3ull * D_DIM * D_DIM * 2;
  int chunk = 1024, sk = 1;
  const int pref[][2] = {{8192, 2}, {4096, 2}, {2048, 2}, {8192, 1},
                         {4096, 1}, {2048, 1}, {1024, 1}};
  for (int i = 0; i < 7; ++i) {
    const int c = pref[i][0], s = pref[i][1];
    size_t R = (size_t)s * c * D_DIM * 4;
    if (R < fixedA) R = fixedA;
    const size_t need = R + 3ull * N_ROWS * D_DIM * 2 + (size_t)c * N_ROWS * 2 +
                        (size_t)c * 128 * 4 + (size_t)c * 4 + 4096;
    if (need <= ws_size) {
      chunk = c;
      sk = s;
      break;
    }
  }

  char* base = (char*)d_ws;
  f16* Xh = (f16*)base;
  f16* WT = (f16*)(base + (size_t)N_ROWS * D_DIM * 2);
  float* Ppart = (float*)base;  // overlays Xh/WT (dead after QKV GEMMs)
  size_t R = (size_t)sk * chunk * D_DIM * 4;
  if (R < fixedA) R = fixedA;
  char* p = base + ((R + 255) & ~(size_t)255);
  f16* Q = (f16*)p;
  p += (size_t)N_ROWS * D_DIM * 2;
  f16* Kh = (f16*)p;
  p += (size_t)N_ROWS * D_DIM * 2;
  f16* VT = (f16*)p;
  p += (size_t)N_ROWS * D_DIM * 2;
  f16* S = (f16*)p;
  p += (size_t)chunk * N_ROWS * 2;
  float* Lpart = (float*)p;
  p += (size_t)chunk * 128 * 4;
  float* linv = (float*)p;

  f32_to_f16_kernel<<<2048, 256, 0, stream>>>(X, Xh, N_ROWS * D_DIM / 4);
  transpose_w_kernel<<<dim3(16, 16, 3), 256, 0, stream>>>(WQ, WK, WV, WT);
  gemm_qkv<<<384, 512, 0, stream>>>(Xh, WT, Q, Kh, VT);

  const int KS = N_ROWS / sk;
  for (int mc = 0; mc < N_ROWS; mc += chunk) {
    const int nyb = chunk / 256;
    gemm_s_exp<<<32 * nyb, 512, 0, stream>>>(Q + (size_t)mc * D_DIM, Kh, S,
                                             Lpart, nyb);
    reduce_l<<<(chunk + 3) / 4, 256, 0, stream>>>(Lpart, linv, chunk);
    gemm_pv<<<4 * nyb * sk, 512, 0, stream>>>(S, VT, Ppart, nyb, KS, chunk);
    reduce_o<<<1024, 256, 0, stream>>>(Ppart, linv, O + (size_t)mc * D_DIM,
                                       chunk, sk);
  }
}